// Round 1
// baseline (493.560 us; speedup 1.0000x reference)
//
#include <hip/hip_runtime.h>
#include <stdint.h>

typedef __bf16 bf16;
typedef __bf16 bf16x4 __attribute__((ext_vector_type(4)));
typedef __bf16 bf16x8 __attribute__((ext_vector_type(8)));
typedef float floatx4 __attribute__((ext_vector_type(4)));

#define B_   2
#define T_   2048
#define E_   2048
#define G_   4
#define QPG_ 4
#define D_   128
#define H_   16        // G*QPG
#define NQ   2048      // H*D
#define NKV  1024      // 2*G*D
#define NQKV 3072
#define M_   4096      // B*T

// async global->LDS, 16B/lane; LDS dst is wave-uniform base + lane*16
__device__ __forceinline__ void gload_lds16(const void* g, void* l) {
  __builtin_amdgcn_global_load_lds(
      (__attribute__((address_space(1))) unsigned int*)g,
      (__attribute__((address_space(3))) unsigned int*)l,
      16, 0, 0);
}

// ---------------- conversion kernels ----------------

__global__ void cast_f32_bf16(const float* __restrict__ in, bf16* __restrict__ out, int n4) {
  int i = blockIdx.x * blockDim.x + threadIdx.x;
  if (i < n4) {
    float4 v = ((const float4*)in)[i];
    bf16x4 o = {(bf16)v.x, (bf16)v.y, (bf16)v.z, (bf16)v.w};
    ((bf16x4*)out)[i] = o;
  }
}

// in: R x C f32 (row-major). out: C x R bf16, row stride out_stride.
__global__ void transpose_cast(const float* __restrict__ in, bf16* __restrict__ out,
                               int R, int C, int out_stride) {
  __shared__ float tile[64][65];
  int r0 = blockIdx.x * 64, c0 = blockIdx.y * 64;
  int tx = threadIdx.x & 63, ty = threadIdx.x >> 6;
  for (int i = ty; i < 64; i += 4)
    tile[i][tx] = in[(size_t)(r0 + i) * C + c0 + tx];
  __syncthreads();
  for (int i = ty; i < 64; i += 4)
    out[(size_t)(c0 + i) * out_stride + r0 + tx] = (bf16)tile[tx][i];
}

__global__ void concat_bias(const float* __restrict__ bq, const float* __restrict__ bkv,
                            float* __restrict__ out) {
  int i = blockIdx.x * 256 + threadIdx.x;  // grid covers exactly 3072
  out[i] = (i < NQ) ? bq[i] : bkv[i - NQ];
}

// ---------------- GEMM: C = A(MxK) * Bt(NxK)^T (+bias) ----------------
// m97 structure: 128x128 tile, BK=32, global_load_lds width16, 16x16x32 bf16 MFMA.

template <int OUT_BF16, int HAS_BIAS>
__global__ __launch_bounds__(256, 2) void gemm_bt(
    const bf16* __restrict__ A, const bf16* __restrict__ Bt,
    const float* __restrict__ bias, void* __restrict__ Cout,
    int M, int N, int K) {
  __shared__ __align__(16) bf16 As[128 * 32];
  __shared__ __align__(16) bf16 Bs[128 * 32];
  const int tid = threadIdx.x;
  const int wave = tid >> 6, lane = tid & 63;
  const int quad = lane >> 4, c = lane & 15;
  const int m0 = blockIdx.x * 128, n0 = blockIdx.y * 128;
  const int wr = (wave >> 1) * 64, wc = (wave & 1) * 64;

  floatx4 acc[4][4];
#pragma unroll
  for (int i = 0; i < 4; ++i)
#pragma unroll
    for (int j = 0; j < 4; ++j) acc[i][j] = (floatx4){0.f, 0.f, 0.f, 0.f};

  // staging: chunk = wave*2+ch covers 16 rows; lane -> row L/4, col (L&3)*8
  const int srow = wave * 32 + (lane >> 2);
  const int scol = (lane & 3) * 8;
  const bf16* Ap = A + (size_t)(m0 + srow) * K + scol;
  const bf16* Bp = Bt + (size_t)(n0 + srow) * K + scol;

  for (int k0 = 0; k0 < K; k0 += 32) {
#pragma unroll
    for (int ch = 0; ch < 2; ++ch) {
      gload_lds16(Ap + (size_t)ch * 16 * K + k0, &As[(wave * 2 + ch) * 512]);
      gload_lds16(Bp + (size_t)ch * 16 * K + k0, &Bs[(wave * 2 + ch) * 512]);
    }
    __syncthreads();
    bf16x8 af[4], bfr[4];
#pragma unroll
    for (int i = 0; i < 4; ++i) {
      af[i]  = *(const bf16x8*)(&As[(wr + i * 16 + c) * 32 + quad * 8]);
      bfr[i] = *(const bf16x8*)(&Bs[(wc + i * 16 + c) * 32 + quad * 8]);
    }
#pragma unroll
    for (int mi = 0; mi < 4; ++mi)
#pragma unroll
      for (int ni = 0; ni < 4; ++ni)
        acc[mi][ni] = __builtin_amdgcn_mfma_f32_16x16x32_bf16(af[mi], bfr[ni], acc[mi][ni], 0, 0, 0);
    __syncthreads();
  }

  float bv[4] = {0.f, 0.f, 0.f, 0.f};
  if (HAS_BIAS) {
#pragma unroll
    for (int ni = 0; ni < 4; ++ni) bv[ni] = bias[n0 + wc + ni * 16 + c];
  }
#pragma unroll
  for (int mi = 0; mi < 4; ++mi) {
#pragma unroll
    for (int ni = 0; ni < 4; ++ni) {
      const int col = n0 + wc + ni * 16 + c;
#pragma unroll
      for (int r = 0; r < 4; ++r) {
        const int row = m0 + wr + mi * 16 + quad * 4 + r;  // C-layout: row=quad*4+reg
        float v = acc[mi][ni][r] + bv[ni];
        if (OUT_BF16)
          ((bf16*)Cout)[(size_t)row * N + col] = (bf16)v;
        else
          ((float*)Cout)[(size_t)row * N + col] = v;
      }
    }
  }
}

// ---------------- PE + layout scatter ----------------

__device__ __forceinline__ float pe_val(int t, int d) {
  int i2 = d & ~1;
  float inv = __expf(-9.210340371976184f * (float)i2 * (1.0f / 128.0f));
  float ang = (float)t * inv;
  return (d & 1) ? cosf(ang) : sinf(ang);
}

// Q[b][h][t][d] = (qkv[.., h*D+d] + pe) / sqrt(D)   (scale folded into Q)
// K[b][g][t][d] =  qkv[.., 2048 + g*256 + d] + pe
__global__ void scatter_qk(const bf16* __restrict__ qkv,
                           bf16* __restrict__ Qb, bf16* __restrict__ Kb) {
  const int row = blockIdx.x;  // 0..4095
  const int b = row >> 11, t = row & 2047;
  const int tid = threadIdx.x;
  const int d = tid & 127;
  const float scale = 0.08838834764831845f;  // 1/sqrt(128)
  const float pe = pe_val(t, d);
  for (int h = tid >> 7; h < H_; h += 2) {
    float q = (float)qkv[(size_t)row * NQKV + h * 128 + d] + pe;
    Qb[((size_t)(b * H_ + h) * T_ + t) * D_ + d] = (bf16)(q * scale);
  }
  for (int g = tid >> 7; g < G_; g += 2) {
    float k = (float)qkv[(size_t)row * NQKV + NQ + g * 256 + d] + pe;
    Kb[((size_t)(b * G_ + g) * T_ + t) * D_ + d] = (bf16)k;
  }
}

// Vt[b][g][d][t] = qkv[b*T+t][2048 + g*256 + 128 + d]  (LDS-tiled transpose)
__global__ void build_vt(const bf16* __restrict__ qkv, bf16* __restrict__ Vt) {
  __shared__ float tile[64][65];
  int t0 = blockIdx.x * 64, d0 = blockIdx.y * 64;
  int bg = blockIdx.z, b = bg >> 2, g = bg & 3;
  const bf16* src = qkv + (size_t)b * T_ * NQKV + NQ + g * 256 + 128;
  bf16* dst = Vt + (size_t)bg * D_ * T_;
  int tx = threadIdx.x & 63, ty = threadIdx.x >> 6;
  for (int i = ty; i < 64; i += 4)
    tile[i][tx] = (float)src[(size_t)(t0 + i) * NQKV + d0 + tx];
  __syncthreads();
  for (int i = ty; i < 64; i += 4)
    dst[(size_t)(d0 + i) * T_ + t0 + tx] = (bf16)tile[tx][i];
}

// ---------------- flash attention ----------------
// grid (T/64, B*H). 4 waves/block, 16 q-rows per wave, 64-key tiles.

__global__ __launch_bounds__(256, 2) void flash_attn(
    const bf16* __restrict__ Qb, const bf16* __restrict__ Kb,
    const bf16* __restrict__ Vt, bf16* __restrict__ Ob) {
  const int qt = blockIdx.x;
  const int bh = blockIdx.y;
  const int b = bh >> 4, h = bh & 15, g = h >> 2;
  const int tid = threadIdx.x;
  const int wave = tid >> 6, lane = tid & 63;
  const int quad = lane >> 4, c = lane & 15;

  __shared__ __align__(16) bf16 Ks[64 * 136];   // [key][d], stride 136 (bank floor)
  __shared__ __align__(16) bf16 Vs[128 * 72];   // [d][key], stride 72
  __shared__ __align__(16) bf16 Ps[4][16 * 72]; // per-wave P round-trip

  const int q0 = qt * 64;
  const int qrow = q0 + wave * 16 + c;  // A-frag: m = lane&15
  const bf16* Qbase = Qb + ((size_t)(b * H_ + h) * T_ + qrow) * D_;
  bf16x8 qf[4];
#pragma unroll
  for (int ks = 0; ks < 4; ++ks)
    qf[ks] = *(const bf16x8*)(Qbase + ks * 32 + quad * 8);

  floatx4 acc[8];
#pragma unroll
  for (int i = 0; i < 8; ++i) acc[i] = (floatx4){0.f, 0.f, 0.f, 0.f};
  float mrow[4] = {-1e30f, -1e30f, -1e30f, -1e30f};
  float lrow[4] = {0.f, 0.f, 0.f, 0.f};

  const bf16* Kg = Kb + (size_t)(b * G_ + g) * T_ * D_;
  const bf16* Vg = Vt + (size_t)(b * G_ + g) * D_ * T_;

  for (int j = 0; j <= qt; ++j) {
    const int j0 = j * 64;
    {  // stage K tile (contiguous 16KB) and Vt tile into padded LDS
      const bf16* src = Kg + (size_t)j0 * D_;
      for (int i = tid; i < 1024; i += 256) {
        int r = i >> 4, c8 = i & 15;
        *(bf16x8*)(&Ks[r * 136 + c8 * 8]) = *(const bf16x8*)(src + r * 128 + c8 * 8);
      }
      for (int i = tid; i < 1024; i += 256) {
        int dd = i >> 3, c8 = i & 7;
        *(bf16x8*)(&Vs[dd * 72 + c8 * 8]) = *(const bf16x8*)(Vg + (size_t)dd * T_ + j0 + c8 * 8);
      }
    }
    __syncthreads();

    // S = Q K^T  (A=Q rows, B=K^T via K row-major reads)
    floatx4 s[4];
#pragma unroll
    for (int n = 0; n < 4; ++n) s[n] = (floatx4){0.f, 0.f, 0.f, 0.f};
#pragma unroll
    for (int ks = 0; ks < 4; ++ks)
#pragma unroll
      for (int n = 0; n < 4; ++n) {
        bf16x8 kf = *(const bf16x8*)(&Ks[(n * 16 + c) * 136 + ks * 32 + quad * 8]);
        s[n] = __builtin_amdgcn_mfma_f32_16x16x32_bf16(qf[ks], kf, s[n], 0, 0, 0);
      }

    if (j == qt) {  // diagonal tile: mask col > row
#pragma unroll
      for (int n = 0; n < 4; ++n)
#pragma unroll
        for (int r = 0; r < 4; ++r)
          if (n * 16 + c > wave * 16 + quad * 4 + r) s[n][r] = -1e30f;
    }

    // online softmax: row stats live in 16 lanes sharing a quad
    float tmax[4];
#pragma unroll
    for (int r = 0; r < 4; ++r)
      tmax[r] = fmaxf(fmaxf(s[0][r], s[1][r]), fmaxf(s[2][r], s[3][r]));
#pragma unroll
    for (int off = 1; off < 16; off <<= 1)
#pragma unroll
      for (int r = 0; r < 4; ++r) tmax[r] = fmaxf(tmax[r], __shfl_xor(tmax[r], off));

    float alpha[4], rsum[4];
#pragma unroll
    for (int r = 0; r < 4; ++r) {
      float mnew = fmaxf(mrow[r], tmax[r]);
      alpha[r] = __expf(mrow[r] - mnew);
      mrow[r] = mnew;
      rsum[r] = 0.f;
    }
    float pvv[4][4];
#pragma unroll
    for (int n = 0; n < 4; ++n)
#pragma unroll
      for (int r = 0; r < 4; ++r) {
        float p = __expf(s[n][r] - mrow[r]);
        pvv[n][r] = p;
        rsum[r] += p;
      }
#pragma unroll
    for (int off = 1; off < 16; off <<= 1)
#pragma unroll
      for (int r = 0; r < 4; ++r) rsum[r] += __shfl_xor(rsum[r], off);
#pragma unroll
    for (int r = 0; r < 4; ++r) lrow[r] = lrow[r] * alpha[r] + rsum[r];
#pragma unroll
    for (int i = 0; i < 8; ++i)
#pragma unroll
      for (int r = 0; r < 4; ++r) acc[i][r] *= alpha[r];

    // P: C-layout -> A-layout via per-wave LDS (same-wave, lgkmcnt-ordered)
    bf16* Pw = &Ps[wave][0];
#pragma unroll
    for (int n = 0; n < 4; ++n)
#pragma unroll
      for (int r = 0; r < 4; ++r)
        Pw[(quad * 4 + r) * 72 + n * 16 + c] = (bf16)pvv[n][r];

    bf16x8 pf[2];
#pragma unroll
    for (int ks = 0; ks < 2; ++ks)
      pf[ks] = *(const bf16x8*)(&Pw[c * 72 + ks * 32 + quad * 8]);

#pragma unroll
    for (int nd = 0; nd < 8; ++nd)
#pragma unroll
      for (int ks = 0; ks < 2; ++ks) {
        bf16x8 vf = *(const bf16x8*)(&Vs[(nd * 16 + c) * 72 + ks * 32 + quad * 8]);
        acc[nd] = __builtin_amdgcn_mfma_f32_16x16x32_bf16(pf[ks], vf, acc[nd], 0, 0, 0);
      }
    __syncthreads();  // protect Ks/Vs before next tile's staging
  }

  float linv[4];
#pragma unroll
  for (int r = 0; r < 4; ++r) linv[r] = 1.f / lrow[r];
#pragma unroll
  for (int nd = 0; nd < 8; ++nd) {
    const int dd = nd * 16 + c;
#pragma unroll
    for (int r = 0; r < 4; ++r) {
      const int trow = q0 + wave * 16 + quad * 4 + r;
      Ob[((size_t)(b * T_ + trow)) * NQ + h * D_ + dd] = (bf16)(acc[nd][r] * linv[r]);
    }
  }
}

// ---------------- launch ----------------

extern "C" void kernel_launch(void* const* d_in, const int* in_sizes, int n_in,
                              void* d_out, int out_size, void* d_ws, size_t ws_size,
                              hipStream_t stream) {
  const float* x   = (const float*)d_in[0];
  const float* wq  = (const float*)d_in[1];
  const float* bq  = (const float*)d_in[2];
  const float* wkv = (const float*)d_in[3];
  const float* bkv = (const float*)d_in[4];
  const float* wo  = (const float*)d_in[5];
  float* out = (float*)d_out;

  char* p = (char*)d_ws;                                   // ~100 MB total
  bf16* xb    = (bf16*)p; p += (size_t)M_ * E_ * 2;        // 16 MB
  bf16* wqkvT = (bf16*)p; p += (size_t)NQKV * E_ * 2;      // 12 MB  [N=3072][K=2048]
  bf16* woT   = (bf16*)p; p += (size_t)E_ * NQ * 2;        // 8 MB   [N=2048][K=2048]
  float* biasq = (float*)p; p += 16384;                    // 3072 f32, padded
  bf16* qkv   = (bf16*)p; p += (size_t)M_ * NQKV * 2;      // 24 MB
  bf16* Qb    = (bf16*)p; p += (size_t)B_ * H_ * T_ * D_ * 2;  // 16 MB
  bf16* Kb    = (bf16*)p; p += (size_t)B_ * G_ * T_ * D_ * 2;  // 4 MB
  bf16* Vtb   = (bf16*)p; p += (size_t)B_ * G_ * D_ * T_ * 2;  // 4 MB
  bf16* Ob    = (bf16*)p; p += (size_t)M_ * NQ * 2;            // 16 MB

  cast_f32_bf16<<<(M_ * E_ / 4) / 256, 256, 0, stream>>>(x, xb, M_ * E_ / 4);
  transpose_cast<<<dim3(E_ / 64, E_ / 64), 256, 0, stream>>>(wq, wqkvT, E_, E_, E_);
  transpose_cast<<<dim3(E_ / 64, NKV / 64), 256, 0, stream>>>(wkv, wqkvT + (size_t)NQ * E_, E_, NKV, E_);
  transpose_cast<<<dim3(E_ / 64, E_ / 64), 256, 0, stream>>>(wo, woT, NQ, E_, NQ);
  concat_bias<<<NQKV / 256, 256, 0, stream>>>(bq, bkv, biasq);

  gemm_bt<1, 1><<<dim3(M_ / 128, NQKV / 128), 256, 0, stream>>>(xb, wqkvT, biasq, qkv, M_, NQKV, E_);
  scatter_qk<<<M_, 256, 0, stream>>>(qkv, Qb, Kb);
  build_vt<<<dim3(T_ / 64, D_ / 64, B_ * G_), 256, 0, stream>>>(qkv, Vtb);
  flash_attn<<<dim3(T_ / 64, B_ * H_), 256, 0, stream>>>(Qb, Kb, Vtb, Ob);
  gemm_bt<0, 0><<<dim3(M_ / 128, E_ / 128), 256, 0, stream>>>(Ob, woT, nullptr, out, M_, E_, NQ);
}

// Round 2
// 416.703 us; speedup vs baseline: 1.1844x; 1.1844x over previous
//
#include <hip/hip_runtime.h>
#include <stdint.h>

typedef __bf16 bf16;
typedef __bf16 bf16x4 __attribute__((ext_vector_type(4)));
typedef __bf16 bf16x8 __attribute__((ext_vector_type(8)));
typedef float floatx4 __attribute__((ext_vector_type(4)));

#define B_   2
#define T_   2048
#define E_   2048
#define G_   4
#define QPG_ 4
#define D_   128
#define H_   16        // G*QPG
#define NQ   2048      // H*D
#define NKV  1024      // 2*G*D
#define NQKV 3072
#define M_   4096      // B*T

// async global->LDS, 16B/lane; LDS dst is wave-uniform base + lane*16
__device__ __forceinline__ void gload_lds16(const void* g, void* l) {
  __builtin_amdgcn_global_load_lds(
      (__attribute__((address_space(1))) unsigned int*)g,
      (__attribute__((address_space(3))) unsigned int*)l,
      16, 0, 0);
}

// ---------------- conversion kernels ----------------

__global__ void cast_f32_bf16(const float* __restrict__ in, bf16* __restrict__ out, int n4) {
  int i = blockIdx.x * blockDim.x + threadIdx.x;
  if (i < n4) {
    float4 v = ((const float4*)in)[i];
    bf16x4 o = {(bf16)v.x, (bf16)v.y, (bf16)v.z, (bf16)v.w};
    ((bf16x4*)out)[i] = o;
  }
}

// in: R x C f32 (row-major). out: C x R bf16, row stride out_stride.
__global__ void transpose_cast(const float* __restrict__ in, bf16* __restrict__ out,
                               int R, int C, int out_stride) {
  __shared__ float tile[64][65];
  int r0 = blockIdx.x * 64, c0 = blockIdx.y * 64;
  int tx = threadIdx.x & 63, ty = threadIdx.x >> 6;
  for (int i = ty; i < 64; i += 4)
    tile[i][tx] = in[(size_t)(r0 + i) * C + c0 + tx];
  __syncthreads();
  for (int i = ty; i < 64; i += 4)
    out[(size_t)(c0 + i) * out_stride + r0 + tx] = (bf16)tile[tx][i];
}

__global__ void concat_bias(const float* __restrict__ bq, const float* __restrict__ bkv,
                            float* __restrict__ out) {
  int i = blockIdx.x * 256 + threadIdx.x;  // grid covers exactly 3072
  out[i] = (i < NQ) ? bq[i] : bkv[i - NQ];
}

// ---------------- GEMM: C = A(MxK) * Bt(NxK)^T (+bias) ----------------
// m97 structure: 128x128 tile, BK=32, global_load_lds width16, 16x16x32 bf16 MFMA.

template <int OUT_BF16, int HAS_BIAS>
__global__ __launch_bounds__(256, 2) void gemm_bt(
    const bf16* __restrict__ A, const bf16* __restrict__ Bt,
    const float* __restrict__ bias, void* __restrict__ Cout,
    int M, int N, int K) {
  __shared__ __align__(16) bf16 As[128 * 32];
  __shared__ __align__(16) bf16 Bs[128 * 32];
  const int tid = threadIdx.x;
  const int wave = tid >> 6, lane = tid & 63;
  const int quad = lane >> 4, c = lane & 15;
  const int m0 = blockIdx.x * 128, n0 = blockIdx.y * 128;
  const int wr = (wave >> 1) * 64, wc = (wave & 1) * 64;

  floatx4 acc[4][4];
#pragma unroll
  for (int i = 0; i < 4; ++i)
#pragma unroll
    for (int j = 0; j < 4; ++j) acc[i][j] = (floatx4){0.f, 0.f, 0.f, 0.f};

  // staging: chunk = wave*2+ch covers 16 rows; lane -> row L/4, col (L&3)*8
  const int srow = wave * 32 + (lane >> 2);
  const int scol = (lane & 3) * 8;
  const bf16* Ap = A + (size_t)(m0 + srow) * K + scol;
  const bf16* Bp = Bt + (size_t)(n0 + srow) * K + scol;

  for (int k0 = 0; k0 < K; k0 += 32) {
#pragma unroll
    for (int ch = 0; ch < 2; ++ch) {
      gload_lds16(Ap + (size_t)ch * 16 * K + k0, &As[(wave * 2 + ch) * 512]);
      gload_lds16(Bp + (size_t)ch * 16 * K + k0, &Bs[(wave * 2 + ch) * 512]);
    }
    __syncthreads();
    bf16x8 af[4], bfr[4];
#pragma unroll
    for (int i = 0; i < 4; ++i) {
      af[i]  = *(const bf16x8*)(&As[(wr + i * 16 + c) * 32 + quad * 8]);
      bfr[i] = *(const bf16x8*)(&Bs[(wc + i * 16 + c) * 32 + quad * 8]);
    }
#pragma unroll
    for (int mi = 0; mi < 4; ++mi)
#pragma unroll
      for (int ni = 0; ni < 4; ++ni)
        acc[mi][ni] = __builtin_amdgcn_mfma_f32_16x16x32_bf16(af[mi], bfr[ni], acc[mi][ni], 0, 0, 0);
    __syncthreads();
  }

  float bv[4] = {0.f, 0.f, 0.f, 0.f};
  if (HAS_BIAS) {
#pragma unroll
    for (int ni = 0; ni < 4; ++ni) bv[ni] = bias[n0 + wc + ni * 16 + c];
  }
#pragma unroll
  for (int mi = 0; mi < 4; ++mi) {
#pragma unroll
    for (int ni = 0; ni < 4; ++ni) {
      const int col = n0 + wc + ni * 16 + c;
#pragma unroll
      for (int r = 0; r < 4; ++r) {
        const int row = m0 + wr + mi * 16 + quad * 4 + r;  // C-layout: row=quad*4+reg
        float v = acc[mi][ni][r] + bv[ni];
        if (OUT_BF16)
          ((bf16*)Cout)[(size_t)row * N + col] = (bf16)v;
        else
          ((float*)Cout)[(size_t)row * N + col] = v;
      }
    }
  }
}

// ---------------- PE + layout scatter ----------------

__device__ __forceinline__ float pe_val(int t, int d) {
  int i2 = d & ~1;
  float inv = __expf(-9.210340371976184f * (float)i2 * (1.0f / 128.0f));
  float ang = (float)t * inv;
  return (d & 1) ? cosf(ang) : sinf(ang);
}

// Q[b][h][t][d] = (qkv[.., h*D+d] + pe) / sqrt(D)   (scale folded into Q)
// K[b][g][t][d] =  qkv[.., 2048 + g*256 + d] + pe
__global__ void scatter_qk(const bf16* __restrict__ qkv,
                           bf16* __restrict__ Qb, bf16* __restrict__ Kb) {
  const int row = blockIdx.x;  // 0..4095
  const int b = row >> 11, t = row & 2047;
  const int tid = threadIdx.x;
  const int d = tid & 127;
  const float scale = 0.08838834764831845f;  // 1/sqrt(128)
  const float pe = pe_val(t, d);
  for (int h = tid >> 7; h < H_; h += 2) {
    float q = (float)qkv[(size_t)row * NQKV + h * 128 + d] + pe;
    Qb[((size_t)(b * H_ + h) * T_ + t) * D_ + d] = (bf16)(q * scale);
  }
  for (int g = tid >> 7; g < G_; g += 2) {
    float k = (float)qkv[(size_t)row * NQKV + NQ + g * 256 + d] + pe;
    Kb[((size_t)(b * G_ + g) * T_ + t) * D_ + d] = (bf16)k;
  }
}

// Vt[b][g][d][t] = qkv[b*T+t][2048 + g*256 + 128 + d]  (LDS-tiled transpose)
__global__ void build_vt(const bf16* __restrict__ qkv, bf16* __restrict__ Vt) {
  __shared__ float tile[64][65];
  int t0 = blockIdx.x * 64, d0 = blockIdx.y * 64;
  int bg = blockIdx.z, b = bg >> 2, g = bg & 3;
  const bf16* src = qkv + (size_t)b * T_ * NQKV + NQ + g * 256 + 128;
  bf16* dst = Vt + (size_t)bg * D_ * T_;
  int tx = threadIdx.x & 63, ty = threadIdx.x >> 6;
  for (int i = ty; i < 64; i += 4)
    tile[i][tx] = (float)src[(size_t)(t0 + i) * NQKV + d0 + tx];
  __syncthreads();
  for (int i = ty; i < 64; i += 4)
    dst[(size_t)(d0 + i) * T_ + t0 + tx] = (bf16)tile[tx][i];
}

// ---------------- flash attention v2 ----------------
// grid (T/64, B*H), qt reversed for scheduling. 4 waves/block, 16 q-rows/wave.
// Double-buffered K/V staged via global_load_lds in m97 chunked layout
// [kc][row][32]; ONE barrier per 64-key tile; prefetch of tile j+1 issued
// right after the barrier so its latency overlaps tile j's compute.

__global__ __launch_bounds__(256, 2) void flash_attn(
    const bf16* __restrict__ Qb, const bf16* __restrict__ Kb,
    const bf16* __restrict__ Vt, bf16* __restrict__ Ob) {
  const int qt = gridDim.x - 1 - blockIdx.x;  // heavy blocks first
  const int bh = blockIdx.y;
  const int b = bh >> 4, h = bh & 15, g = h >> 2;
  const int tid = threadIdx.x;
  const int wave = tid >> 6, lane = tid & 63;
  const int quad = lane >> 4, c = lane & 15;

  __shared__ __align__(16) bf16 Ks[2][4][64 * 32];   // [buf][kc][key][32]  32 KB
  __shared__ __align__(16) bf16 Vs[2][2][128 * 32];  // [buf][kc][d][32]    32 KB
  __shared__ __align__(16) bf16 Ps[4][16 * 72];      // per-wave P, stride 72 (16B rows)

  const int q0 = qt * 64;
  const int qrow = q0 + wave * 16 + c;  // A-frag: m = lane&15
  const bf16* Qbase = Qb + ((size_t)(b * H_ + h) * T_ + qrow) * D_;
  bf16x8 qf[4];
#pragma unroll
  for (int ks = 0; ks < 4; ++ks)
    qf[ks] = *(const bf16x8*)(Qbase + ks * 32 + quad * 8);

  floatx4 acc[8];
#pragma unroll
  for (int i = 0; i < 8; ++i) acc[i] = (floatx4){0.f, 0.f, 0.f, 0.f};
  float mrow[4] = {-1e30f, -1e30f, -1e30f, -1e30f};
  float lsum[4] = {0.f, 0.f, 0.f, 0.f};

  const bf16* Kg = Kb + (size_t)(b * G_ + g) * T_ * D_;
  const bf16* Vg = Vt + (size_t)(b * G_ + g) * D_ * T_;

  // staging lane coords: lane L -> row L/4, col (L&3)*8 within a [16][32] issue
  const int slr = lane >> 2;
  const int slc = (lane & 3) * 8;

  // prologue: stage tile 0 into buffer 0
  {
    const bf16* ksrc = Kg + (size_t)(wave * 16 + slr) * D_ + slc;
#pragma unroll
    for (int kc = 0; kc < 4; ++kc)
      gload_lds16(ksrc + kc * 32, &Ks[0][kc][wave * 16 * 32]);
#pragma unroll
    for (int s = 0; s < 2; ++s) {
      const bf16* vsrc = Vg + (size_t)(wave * 32 + s * 16 + slr) * T_ + slc;
#pragma unroll
      for (int kc = 0; kc < 2; ++kc)
        gload_lds16(vsrc + kc * 32, &Vs[0][kc][(wave * 32 + s * 16) * 32]);
    }
  }

  for (int j = 0; j <= qt; ++j) {
    __syncthreads();  // drains vmcnt: buf[j&1] is ready; prev tile's reads done

    if (j < qt) {  // prefetch tile j+1 into the other buffer (overlaps compute)
      const int nb = (j + 1) & 1;
      const int j0n = (j + 1) * 64;
      const bf16* ksrc = Kg + (size_t)(j0n + wave * 16 + slr) * D_ + slc;
#pragma unroll
      for (int kc = 0; kc < 4; ++kc)
        gload_lds16(ksrc + kc * 32, &Ks[nb][kc][wave * 16 * 32]);
#pragma unroll
      for (int s = 0; s < 2; ++s) {
        const bf16* vsrc = Vg + (size_t)(wave * 32 + s * 16 + slr) * T_ + j0n + slc;
#pragma unroll
        for (int kc = 0; kc < 2; ++kc)
          gload_lds16(vsrc + kc * 32, &Vs[nb][kc][(wave * 32 + s * 16) * 32]);
      }
    }

    const bf16* Kt = &Ks[j & 1][0][0];
    const bf16* Vtile = &Vs[j & 1][0][0];

    // S = Q K^T
    floatx4 s[4];
#pragma unroll
    for (int n = 0; n < 4; ++n) s[n] = (floatx4){0.f, 0.f, 0.f, 0.f};
#pragma unroll
    for (int ks = 0; ks < 4; ++ks)
#pragma unroll
      for (int n = 0; n < 4; ++n) {
        bf16x8 kf = *(const bf16x8*)(Kt + ks * 2048 + (n * 16 + c) * 32 + quad * 8);
        s[n] = __builtin_amdgcn_mfma_f32_16x16x32_bf16(qf[ks], kf, s[n], 0, 0, 0);
      }

    if (j == qt) {  // diagonal tile: mask col > row
#pragma unroll
      for (int n = 0; n < 4; ++n)
#pragma unroll
        for (int r = 0; r < 4; ++r)
          if (n * 16 + c > wave * 16 + quad * 4 + r) s[n][r] = -1e30f;
    }

    // online softmax: row stats across the 16 lanes of a quad-row
    float tmax[4];
#pragma unroll
    for (int r = 0; r < 4; ++r)
      tmax[r] = fmaxf(fmaxf(s[0][r], s[1][r]), fmaxf(s[2][r], s[3][r]));
#pragma unroll
    for (int off = 1; off < 16; off <<= 1)
#pragma unroll
      for (int r = 0; r < 4; ++r) tmax[r] = fmaxf(tmax[r], __shfl_xor(tmax[r], off));

    float alpha[4], rsum[4];
#pragma unroll
    for (int r = 0; r < 4; ++r) {
      float mnew = fmaxf(mrow[r], tmax[r]);
      alpha[r] = __expf(mrow[r] - mnew);
      mrow[r] = mnew;
      rsum[r] = 0.f;
    }
    float pvv[4][4];
#pragma unroll
    for (int n = 0; n < 4; ++n)
#pragma unroll
      for (int r = 0; r < 4; ++r) {
        float p = __expf(s[n][r] - mrow[r]);
        pvv[n][r] = p;
        rsum[r] += p;
      }
#pragma unroll
    for (int off = 1; off < 16; off <<= 1)
#pragma unroll
      for (int r = 0; r < 4; ++r) rsum[r] += __shfl_xor(rsum[r], off);
#pragma unroll
    for (int r = 0; r < 4; ++r) lsum[r] = lsum[r] * alpha[r] + rsum[r];
#pragma unroll
    for (int i = 0; i < 8; ++i)
#pragma unroll
      for (int r = 0; r < 4; ++r) acc[i][r] *= alpha[r];

    // P: C-layout -> A-layout via per-wave LDS (same-wave, lgkmcnt-ordered)
    bf16* Pw = &Ps[wave][0];
#pragma unroll
    for (int n = 0; n < 4; ++n)
#pragma unroll
      for (int r = 0; r < 4; ++r)
        Pw[(quad * 4 + r) * 72 + n * 16 + c] = (bf16)pvv[n][r];

    bf16x8 pf[2];
#pragma unroll
    for (int ks = 0; ks < 2; ++ks)
      pf[ks] = *(const bf16x8*)(&Pw[c * 72 + ks * 32 + quad * 8]);

#pragma unroll
    for (int nd = 0; nd < 8; ++nd)
#pragma unroll
      for (int ks = 0; ks < 2; ++ks) {
        bf16x8 vf = *(const bf16x8*)(Vtile + ks * 4096 + (nd * 16 + c) * 32 + quad * 8);
        acc[nd] = __builtin_amdgcn_mfma_f32_16x16x32_bf16(pf[ks], vf, acc[nd], 0, 0, 0);
      }
  }

  float linv[4];
#pragma unroll
  for (int r = 0; r < 4; ++r) linv[r] = 1.f / lsum[r];
#pragma unroll
  for (int nd = 0; nd < 8; ++nd) {
    const int dd = nd * 16 + c;
#pragma unroll
    for (int r = 0; r < 4; ++r) {
      const int trow = q0 + wave * 16 + quad * 4 + r;
      Ob[((size_t)(b * T_ + trow)) * NQ + h * D_ + dd] = (bf16)(acc[nd][r] * linv[r]);
    }
  }
}

// ---------------- launch ----------------

extern "C" void kernel_launch(void* const* d_in, const int* in_sizes, int n_in,
                              void* d_out, int out_size, void* d_ws, size_t ws_size,
                              hipStream_t stream) {
  const float* x   = (const float*)d_in[0];
  const float* wq  = (const float*)d_in[1];
  const float* bq  = (const float*)d_in[2];
  const float* wkv = (const float*)d_in[3];
  const float* bkv = (const float*)d_in[4];
  const float* wo  = (const float*)d_in[5];
  float* out = (float*)d_out;

  char* p = (char*)d_ws;                                   // ~100 MB total
  bf16* xb    = (bf16*)p; p += (size_t)M_ * E_ * 2;        // 16 MB
  bf16* wqkvT = (bf16*)p; p += (size_t)NQKV * E_ * 2;      // 12 MB  [N=3072][K=2048]
  bf16* woT   = (bf16*)p; p += (size_t)E_ * NQ * 2;        // 8 MB   [N=2048][K=2048]
  float* biasq = (float*)p; p += 16384;                    // 3072 f32, padded
  bf16* qkv   = (bf16*)p; p += (size_t)M_ * NQKV * 2;      // 24 MB
  bf16* Qb    = (bf16*)p; p += (size_t)B_ * H_ * T_ * D_ * 2;  // 16 MB
  bf16* Kb    = (bf16*)p; p += (size_t)B_ * G_ * T_ * D_ * 2;  // 4 MB
  bf16* Vtb   = (bf16*)p; p += (size_t)B_ * G_ * D_ * T_ * 2;  // 4 MB
  bf16* Ob    = (bf16*)p; p += (size_t)M_ * NQ * 2;            // 16 MB

  cast_f32_bf16<<<(M_ * E_ / 4) / 256, 256, 0, stream>>>(x, xb, M_ * E_ / 4);
  transpose_cast<<<dim3(E_ / 64, E_ / 64), 256, 0, stream>>>(wq, wqkvT, E_, E_, E_);
  transpose_cast<<<dim3(E_ / 64, NKV / 64), 256, 0, stream>>>(wkv, wqkvT + (size_t)NQ * E_, E_, NKV, E_);
  transpose_cast<<<dim3(E_ / 64, E_ / 64), 256, 0, stream>>>(wo, woT, NQ, E_, NQ);
  concat_bias<<<NQKV / 256, 256, 0, stream>>>(bq, bkv, biasq);

  gemm_bt<1, 1><<<dim3(M_ / 128, NQKV / 128), 256, 0, stream>>>(xb, wqkvT, biasq, qkv, M_, NQKV, E_);
  scatter_qk<<<M_, 256, 0, stream>>>(qkv, Qb, Kb);
  build_vt<<<dim3(T_ / 64, D_ / 64, B_ * G_), 256, 0, stream>>>(qkv, Vtb);
  flash_attn<<<dim3(T_ / 64, B_ * H_), 256, 0, stream>>>(Qb, Kb, Vtb, Ob);
  gemm_bt<0, 0><<<dim3(M_ / 128, E_ / 128), 256, 0, stream>>>(Ob, woT, nullptr, out, M_, E_, NQ);
}